// Round 8
// baseline (254.761 us; speedup 1.0000x reference)
//
#include <hip/hip_runtime.h>
#include <math.h>

// Problem sizes (fixed by setup_inputs)
constexpr int N_V  = 16384;       // original vertices
constexpr int N_F  = 16384;       // original faces (targets for fwd)
constexpr int G_F  = 8192;        // simplified faces (queries for fwd)
constexpr int NS   = 16;          // samples per face
constexpr int NPTS = G_F * NS;    // 131072 sample points (queries for rev)

constexpr int TILES = 32;         // B-tiles staged per LDS chunk (32 KB)

typedef _Float16 half8 __attribute__((ext_vector_type(8)));
typedef float    f32x16 __attribute__((ext_vector_type(16)));

// ---------------- workspace layout (float4 units first, 16B aligned) ----------
constexpr int F4_ACC   = 0;                    // 1  float4: acc[0]=sum p*d, acc[1]=max d (uint bits)
constexpr int F4_SB    = 1;                    // [G_F]  simp barycenters x,y,z,|b|^2
constexpr int F4_PTS   = F4_SB + G_F;          // [NPTS] sample points    x,y,z,|p|^2
constexpr int F4_PKV   = F4_PTS + NPTS;        // packed verts: 512 tiles * 64 * 16B
constexpr int F4_PKO   = F4_PKV + 32768;       // packed obary: 512 tiles * 64 * 16B
constexpr int F4_TOTAL = F4_PKO + 32768;
constexpr int WS_MINF  = F4_TOTAL * 4;         // [G_F]  fwd min d^2 (uint bits)

// Two MFMAs (one tile-pair) + 6x s_nop 7 hazard pad, dsts FORCED to arch
// VGPRs.  48-cycle pad after the last MFMA is the round-7-proven-good
// constant (round 6, unpadded: absmax 454; round 7, 48 cyc: absmax 0).
// In the pipelined loop the consumer min3s run one iteration later, adding
// another >=10 cyc of issue distance on top of the 42 in-block cycles.
__device__ __forceinline__ void mfma2(half8 a, half8 cA, half8 cB,
                                      f32x16& dA, f32x16& dB) {
  asm volatile(
      "v_mfma_f32_32x32x16_f16 %0, %2, %3, 0\n\t"
      "v_mfma_f32_32x32x16_f16 %1, %2, %4, 0\n\t"
      "s_nop 7\n\t" "s_nop 7\n\t" "s_nop 7\n\t"
      "s_nop 7\n\t" "s_nop 7\n\t" "s_nop 7"
      : "=&v"(dA), "=&v"(dB)
      : "v"(a), "v"(cA), "v"(cB));
}

// Pack one target (x,y,z,sq) into B-fragment order (validated: absmax=0):
// col n = lane&31, k = (lane>>5)*8 + j.
// k0-3 = hi(-2x,-2y,-2z,|v|^2), k4-7 = lo residuals, k8-11 = hi again, k12-15 = 0.
__device__ __forceinline__ void pack_target(float x, float y, float z, float sq,
                                            half8* __restrict__ pk, int tile, int n) {
  float ax = -2.0f*x, ay = -2.0f*y, az = -2.0f*z;
  _Float16 hx = (_Float16)ax, hy = (_Float16)ay, hz = (_Float16)az, hw = (_Float16)sq;
  _Float16 lx = (_Float16)(ax - (float)hx), ly = (_Float16)(ay - (float)hy);
  _Float16 lz = (_Float16)(az - (float)hz), lw = (_Float16)(sq - (float)hw);
  half8 h0; h0[0]=hx; h0[1]=hy; h0[2]=hz; h0[3]=hw; h0[4]=lx; h0[5]=ly; h0[6]=lz; h0[7]=lw;
  half8 h1; h1[0]=hx; h1[1]=hy; h1[2]=hz; h1[3]=hw;
  h1[4]=(_Float16)0.0f; h1[5]=(_Float16)0.0f; h1[6]=(_Float16)0.0f; h1[7]=(_Float16)0.0f;
  pk[(size_t)tile*64 + n]      = h0;
  pk[(size_t)tile*64 + 32 + n] = h1;
}

// Fused prep, one thread per sample point.
__global__ void k_prep(const float* __restrict__ ov, const int* __restrict__ of,
                       const float* __restrict__ sv, const int* __restrict__ sf,
                       const float* __restrict__ r1, const float* __restrict__ r2,
                       unsigned int* __restrict__ ws, float4* __restrict__ ws4) {
  int i = blockIdx.x * blockDim.x + threadIdx.x;
  if (i < 4) ws[i] = 0u;                          // acc: sum=0.0f, max=0 bits

  { // sample point i (face verts are 96 KB total -> L1/L2-hot gathers)
    int g = i >> 4;
    int a = sf[3*g], b = sf[3*g+1], c = sf[3*g+2];
    float sr = sqrtf(r1[i]);
    float u = 1.0f - sr;
    float v = sr * (1.0f - r2[i]);
    float w = sr * r2[i];
    float px = u*sv[3*a]   + v*sv[3*b]   + w*sv[3*c];
    float py = u*sv[3*a+1] + v*sv[3*b+1] + w*sv[3*c+1];
    float pz = u*sv[3*a+2] + v*sv[3*b+2] + w*sv[3*c+2];
    (ws4 + F4_PTS)[i] = make_float4(px, py, pz, fmaf(px, px, fmaf(py, py, pz*pz)));
  }
  if (i < G_F) { // simp barycenter (fwd query) + minf init
    ws[WS_MINF + i] = 0x7f800000u;
    int a = sf[3*i], b = sf[3*i+1], c = sf[3*i+2];
    float x = (sv[3*a] + sv[3*b] + sv[3*c]) * (1.0f/3.0f);
    float y = (sv[3*a+1] + sv[3*b+1] + sv[3*c+1]) * (1.0f/3.0f);
    float z = (sv[3*a+2] + sv[3*b+2] + sv[3*c+2]) * (1.0f/3.0f);
    (ws4 + F4_SB)[i] = make_float4(x, y, z, fmaf(x, x, fmaf(y, y, z*z)));
  }
  if (i < N_V) { // packed vertices (rev targets)
    float x = ov[3*i], y = ov[3*i+1], z = ov[3*i+2];
    pack_target(x, y, z, fmaf(x, x, fmaf(y, y, z*z)),
                (half8*)(ws4 + F4_PKV), i >> 5, i & 31);
  }
  if (i < N_F) { // packed orig barycenters (fwd targets)
    int a = of[3*i], b = of[3*i+1], c = of[3*i+2];
    float x = (ov[3*a] + ov[3*b] + ov[3*c]) * (1.0f/3.0f);
    float y = (ov[3*a+1] + ov[3*b+1] + ov[3*c+1]) * (1.0f/3.0f);
    float z = (ov[3*a+2] + ov[3*b+2] + ov[3*c+2]) * (1.0f/3.0f);
    pack_target(x, y, z, fmaf(x, x, fmaf(y, y, z*z)),
                (half8*)(ws4 + F4_PKO), i >> 5, i & 31);
  }
}

__device__ __forceinline__ float waveSum(float v) {
  #pragma unroll
  for (int o = 32; o > 0; o >>= 1) v += __shfl_down(v, o, 64);
  return v;
}
__device__ __forceinline__ float waveMax(float v) {
  #pragma unroll
  for (int o = 32; o > 0; o >>= 1) v = fmaxf(v, __shfl_down(v, o, 64));
  return v;
}

// MFMA min-distance kernel, LDS-staged, software-pipelined asm MFMA.
// MB=1: wave owns 32 queries; block = 128 queries (4 waves).  Per chunk,
// 32 B-tiles staged to LDS (async, w16), then a pipelined sweep: issue
// MFMA pair p, min3-consume pair p-1 (d[2][2] parity buffers, fully
// unrolled -> no copies).  Arch liveness ~110 regs -> launch_bounds(256,4)
// keeps rm in VGPRs (round-7 failure: everything but asm dsts AGPR'd).
// REV: epilogue accumulates sum(p*d) and max(d) via atomics (k-split=1,
// final min known here -> no minr array, no reduce pass).
// FWD: epilogue atomicMin into minU (k-split > 1).
template <bool REV>
__global__ __launch_bounds__(256, 4) void k_min(const float4* __restrict__ q4,
                                                const half8* __restrict__ pk,
                                                unsigned int* __restrict__ minU,
                                                const float* __restrict__ probs,
                                                float* __restrict__ acc,
                                                int nchunks) {
  __shared__ half8 sB[TILES * 64];   // 32 KB
  int lane  = threadIdx.x & 63;
  int wave  = threadIdx.x >> 6;
  int half_ = lane >> 5;
  int m     = lane & 31;
  int qbase = blockIdx.x * 128 + wave * 32;
  int tbase = blockIdx.y * nchunks * TILES;

  // A fragment (validated): A[m=lane&31][k=(lane>>5)*8+j]
  // half0: (p_hi,1, p_hi,1)   half1: (p_lo,0, 0,0,0,0)
  float4 q = q4[qbase + m];
  float psq = q.w;
  half8 af;
  {
    _Float16 hx = (_Float16)q.x, hy = (_Float16)q.y, hz = (_Float16)q.z;
    if (half_ == 0) {
      af[0]=hx; af[1]=hy; af[2]=hz; af[3]=(_Float16)1.0f;
      af[4]=hx; af[5]=hy; af[6]=hz; af[7]=(_Float16)1.0f;
    } else {
      af[0]=(_Float16)(q.x-(float)hx); af[1]=(_Float16)(q.y-(float)hy);
      af[2]=(_Float16)(q.z-(float)hz); af[3]=(_Float16)0.0f;
      af[4]=(_Float16)0.0f; af[5]=(_Float16)0.0f; af[6]=(_Float16)0.0f; af[7]=(_Float16)0.0f;
    }
  }

  float inf = __uint_as_float(0x7f800000u);
  float rm[16];
  #pragma unroll
  for (int r = 0; r < 16; ++r) rm[r] = inf;

  for (int ch = 0; ch < nchunks; ++ch) {
    int t0 = tbase + ch * TILES;
    if (ch > 0) __syncthreads();   // prior sweep done before overwriting sB
    // async stage: wave w loads tiles w, w+4, ..., w+28 (1 KB each, lane*16B)
    const half8* src = pk + (size_t)(t0 + wave) * 64 + lane;
    #pragma unroll
    for (int j = 0; j < TILES/4; ++j) {
      __builtin_amdgcn_global_load_lds(
          (const __attribute__((address_space(1))) unsigned int*)(src + (size_t)j*256),
          (__attribute__((address_space(3))) unsigned int*)&sB[(wave + 4*j) * 64],
          16, 0, 0);
    }
    __syncthreads();               // vmcnt(0) drained -> tiles resident

    // pipelined sweep over 16 tile-pairs
    f32x16 d[2][2];
    {
      half8 cA = sB[lane];
      half8 cB = sB[64 + lane];
      mfma2(af, cA, cB, d[0][0], d[0][1]);
    }
    #pragma unroll
    for (int p = 1; p < TILES/2; ++p) {
      half8 nA = sB[(2*p)*64 + lane];        // ds_read_b128
      half8 nB = sB[(2*p)*64 + 64 + lane];
      mfma2(af, nA, nB, d[p&1][0], d[p&1][1]);
      int o = (p-1) & 1;
      #pragma unroll
      for (int r = 0; r < 16; ++r)
        rm[r] = fminf(fminf(rm[r], d[o][0][r]), d[o][1][r]);  // v_min3_f32
    }
    asm volatile("s_nop 7\n\ts_nop 7\n\ts_nop 7\n\ts_nop 7\n\ts_nop 7\n\ts_nop 7");
    int o = (TILES/2 - 1) & 1;   // last pair's parity
    #pragma unroll
    for (int r = 0; r < 16; ++r)
      rm[r] = fminf(fminf(rm[r], d[o][0][r]), d[o][1][r]);
  }

  // column-min across 32 targets; C/D: col=lane&31, row=(r&3)+8*(r>>2)+4*half
  float ps = 0.0f, pm = 0.0f;
  #pragma unroll
  for (int r = 0; r < 16; ++r) {
    float v = rm[r];
    v = fminf(v, __shfl_xor(v, 1, 64));
    v = fminf(v, __shfl_xor(v, 2, 64));
    v = fminf(v, __shfl_xor(v, 4, 64));
    v = fminf(v, __shfl_xor(v, 8, 64));
    v = fminf(v, __shfl_xor(v, 16, 64));
    int row = (r & 3) + 8*(r >> 2) + 4*half_;
    if (m == row) {
      float d2 = fmaxf(psq + v, 0.0f);
      if (REV) {
        float dd = sqrtf(fmaxf(d2, 1e-12f));
        ps = fmaf(probs[(qbase + row) >> 4], dd, ps);
        pm = fmaxf(pm, dd);
      } else {
        atomicMin(&minU[qbase + row], __float_as_uint(d2));
      }
    }
  }
  if (REV) {
    ps = waveSum(ps);
    pm = waveMax(pm);
    if (lane == 0) {
      atomicAdd(&acc[0], ps);
      atomicMax((unsigned int*)&acc[1], __float_as_uint(pm));
    }
  }
}

// Final: reduce fwd minf (8192) + combine with rev accumulators.  1 block.
__global__ void k_fin(const float* __restrict__ minf, const float* __restrict__ probs,
                      const float* __restrict__ acc, float* __restrict__ out) {
  int tid = threadIdx.x;
  float sf = 0.0f;
  for (int i = tid; i < G_F; i += 256) {
    float df = sqrtf(fmaxf(minf[i], 1e-12f));
    sf = fmaf(probs[i], df, sf);
    sf = fmaf(1e-4f, 1.0f - probs[i], sf);
  }
  __shared__ float l[4];
  int lane = tid & 63, wid = tid >> 6;
  sf = waveSum(sf);
  if (lane == 0) l[wid] = sf;
  __syncthreads();
  if (tid == 0) {
    float t = l[0] + l[1] + l[2] + l[3];
    float maxd = acc[1] + 1e-8f;          // uint-ordered bits == float (d>=0)
    out[0] = t + acc[0] * 0.1f / maxd;
  }
}

extern "C" void kernel_launch(void* const* d_in, const int* in_sizes, int n_in,
                              void* d_out, int out_size, void* d_ws, size_t ws_size,
                              hipStream_t stream) {
  const float* ov    = (const float*)d_in[0];
  const int*   of    = (const int*)  d_in[1];
  const float* sv    = (const float*)d_in[2];
  const int*   sfc   = (const int*)  d_in[3];
  const float* probs = (const float*)d_in[4];
  const float* r1    = (const float*)d_in[5];
  const float* r2    = (const float*)d_in[6];
  float*  ws  = (float*)d_ws;
  float4* ws4 = (float4*)d_ws;
  float*  out = (float*)d_out;

  float*        acc   = ws;
  float4*       sb4   = ws4 + F4_SB;
  float4*       pts4  = ws4 + F4_PTS;
  half8*        pkV   = (half8*)(ws4 + F4_PKV);
  half8*        pkO   = (half8*)(ws4 + F4_PKO);
  unsigned int* minfU = (unsigned int*)(ws + WS_MINF);
  const float*  minfF = ws + WS_MINF;

  k_prep<<<NPTS/256, 256, 0, stream>>>(ov, of, sv, sfc, r1, r2,
                                       (unsigned int*)ws, ws4);
  // fwd: 8192 queries (64 blocks.x), 512 obary tiles, ksplit 8 -> 2 chunks
  k_min<false><<<dim3(G_F/128, 8), 256, 0, stream>>>(sb4, pkO, minfU,
                                                     nullptr, nullptr, 2);
  // rev: 131072 queries (1024 blocks.x), 512 vert tiles, ksplit 1 -> 16 chunks
  k_min<true><<<dim3(NPTS/128, 1), 256, 0, stream>>>(pts4, pkV, nullptr,
                                                     probs, acc, 16);
  k_fin<<<1, 256, 0, stream>>>(minfF, probs, acc, out);
}

// Round 9
// 191.805 us; speedup vs baseline: 1.3282x; 1.3282x over previous
//
#include <hip/hip_runtime.h>
#include <math.h>

// Problem sizes (fixed by setup_inputs)
constexpr int N_V  = 16384;       // original vertices
constexpr int N_F  = 16384;       // original faces (targets for fwd)
constexpr int G_F  = 8192;        // simplified faces (queries for fwd)
constexpr int NS   = 16;          // samples per face
constexpr int NPTS = G_F * NS;    // 131072 sample points (queries for rev)

constexpr int MB    = 2;          // 32-row query blocks per wave (64 queries/wave)
constexpr int TILES = 32;         // B-tiles staged per LDS chunk (32 KB)

typedef _Float16 half8 __attribute__((ext_vector_type(8)));

// ---------------- workspace layout (float4 units first, 16B aligned) ----------
constexpr int F4_ACC   = 0;                    // 1  float4: accumulators
constexpr int F4_SB    = 1;                    // [G_F]  simp barycenters x,y,z,|b|^2
constexpr int F4_PTS   = F4_SB + G_F;          // [NPTS] sample points    x,y,z,|p|^2
constexpr int F4_PKV   = F4_PTS + NPTS;        // packed verts: 512 tiles * 64 * 16B
constexpr int F4_PKO   = F4_PKV + 32768;       // packed obary: 512 tiles * 64 * 16B
constexpr int F4_TOTAL = F4_PKO + 32768;
constexpr int WS_MINF  = F4_TOTAL * 4;         // [G_F]  fwd min d^2 (uint bits)
constexpr int WS_MINR  = WS_MINF + G_F;        // [NPTS] rev min d^2 (uint bits)

// 4 MFMAs (4 B-tiles x 1 A-frag) with dsts HARD-PINNED to v[32:95] (clobbers),
// 48-cycle pad (round-6/7 A/B-proven constant), then 32 v_min3_f32 performed
// INSIDE the asm on 16 "+v"-constrained rm floats.  This removes the allocator
// from the MFMA-dst/min path entirely — rounds 3-8 all failed because rm (or
// the dsts) silently went to AGPRs and every min became accvgpr_read churn.
// Hazard spacing: tiles 0/1 mins run first (>=56 cyc after their MFMAs),
// tiles 2/3 mins run last (>=80 cyc).  WAR across blocks is safe: a prior
// block's min3 reads complete at issue, >=32 cyc before the next block's
// XDL writes land.
#define MFMA4_MIN(AF, C0, C1, C2, C3, RM)                                   \
  asm volatile(                                                             \
    "v_mfma_f32_32x32x16_f16 v[32:47], %16, %17, 0\n\t"                     \
    "v_mfma_f32_32x32x16_f16 v[48:63], %16, %18, 0\n\t"                     \
    "v_mfma_f32_32x32x16_f16 v[64:79], %16, %19, 0\n\t"                     \
    "v_mfma_f32_32x32x16_f16 v[80:95], %16, %20, 0\n\t"                     \
    "s_nop 7\n\ts_nop 7\n\ts_nop 7\n\ts_nop 7\n\ts_nop 7\n\ts_nop 7\n\t"    \
    "v_min3_f32 %0,  %0,  v32, v48\n\t"                                     \
    "v_min3_f32 %1,  %1,  v33, v49\n\t"                                     \
    "v_min3_f32 %2,  %2,  v34, v50\n\t"                                     \
    "v_min3_f32 %3,  %3,  v35, v51\n\t"                                     \
    "v_min3_f32 %4,  %4,  v36, v52\n\t"                                     \
    "v_min3_f32 %5,  %5,  v37, v53\n\t"                                     \
    "v_min3_f32 %6,  %6,  v38, v54\n\t"                                     \
    "v_min3_f32 %7,  %7,  v39, v55\n\t"                                     \
    "v_min3_f32 %8,  %8,  v40, v56\n\t"                                     \
    "v_min3_f32 %9,  %9,  v41, v57\n\t"                                     \
    "v_min3_f32 %10, %10, v42, v58\n\t"                                     \
    "v_min3_f32 %11, %11, v43, v59\n\t"                                     \
    "v_min3_f32 %12, %12, v44, v60\n\t"                                     \
    "v_min3_f32 %13, %13, v45, v61\n\t"                                     \
    "v_min3_f32 %14, %14, v46, v62\n\t"                                     \
    "v_min3_f32 %15, %15, v47, v63\n\t"                                     \
    "v_min3_f32 %0,  %0,  v64, v80\n\t"                                     \
    "v_min3_f32 %1,  %1,  v65, v81\n\t"                                     \
    "v_min3_f32 %2,  %2,  v66, v82\n\t"                                     \
    "v_min3_f32 %3,  %3,  v67, v83\n\t"                                     \
    "v_min3_f32 %4,  %4,  v68, v84\n\t"                                     \
    "v_min3_f32 %5,  %5,  v69, v85\n\t"                                     \
    "v_min3_f32 %6,  %6,  v70, v86\n\t"                                     \
    "v_min3_f32 %7,  %7,  v71, v87\n\t"                                     \
    "v_min3_f32 %8,  %8,  v72, v88\n\t"                                     \
    "v_min3_f32 %9,  %9,  v73, v89\n\t"                                     \
    "v_min3_f32 %10, %10, v74, v90\n\t"                                     \
    "v_min3_f32 %11, %11, v75, v91\n\t"                                     \
    "v_min3_f32 %12, %12, v76, v92\n\t"                                     \
    "v_min3_f32 %13, %13, v77, v93\n\t"                                     \
    "v_min3_f32 %14, %14, v78, v94\n\t"                                     \
    "v_min3_f32 %15, %15, v79, v95"                                         \
    : "+v"(RM[0]),  "+v"(RM[1]),  "+v"(RM[2]),  "+v"(RM[3]),                \
      "+v"(RM[4]),  "+v"(RM[5]),  "+v"(RM[6]),  "+v"(RM[7]),                \
      "+v"(RM[8]),  "+v"(RM[9]),  "+v"(RM[10]), "+v"(RM[11]),               \
      "+v"(RM[12]), "+v"(RM[13]), "+v"(RM[14]), "+v"(RM[15])                \
    : "v"(AF), "v"(C0), "v"(C1), "v"(C2), "v"(C3)                           \
    : "v32","v33","v34","v35","v36","v37","v38","v39",                      \
      "v40","v41","v42","v43","v44","v45","v46","v47",                      \
      "v48","v49","v50","v51","v52","v53","v54","v55",                      \
      "v56","v57","v58","v59","v60","v61","v62","v63",                      \
      "v64","v65","v66","v67","v68","v69","v70","v71",                      \
      "v72","v73","v74","v75","v76","v77","v78","v79",                      \
      "v80","v81","v82","v83","v84","v85","v86","v87",                      \
      "v88","v89","v90","v91","v92","v93","v94","v95")

// Pack one target (x,y,z,sq) into B-fragment order (validated: absmax=0):
// col n = lane&31, k = (lane>>5)*8 + j.
// k0-3 = hi(-2x,-2y,-2z,|v|^2), k4-7 = lo residuals, k8-11 = hi again, k12-15 = 0.
__device__ __forceinline__ void pack_target(float x, float y, float z, float sq,
                                            half8* __restrict__ pk, int tile, int n) {
  float ax = -2.0f*x, ay = -2.0f*y, az = -2.0f*z;
  _Float16 hx = (_Float16)ax, hy = (_Float16)ay, hz = (_Float16)az, hw = (_Float16)sq;
  _Float16 lx = (_Float16)(ax - (float)hx), ly = (_Float16)(ay - (float)hy);
  _Float16 lz = (_Float16)(az - (float)hz), lw = (_Float16)(sq - (float)hw);
  half8 h0; h0[0]=hx; h0[1]=hy; h0[2]=hz; h0[3]=hw; h0[4]=lx; h0[5]=ly; h0[6]=lz; h0[7]=lw;
  half8 h1; h1[0]=hx; h1[1]=hy; h1[2]=hz; h1[3]=hw;
  h1[4]=(_Float16)0.0f; h1[5]=(_Float16)0.0f; h1[6]=(_Float16)0.0f; h1[7]=(_Float16)0.0f;
  pk[(size_t)tile*64 + n]      = h0;
  pk[(size_t)tile*64 + 32 + n] = h1;
}

// Fused prep, one thread per sample point.
__global__ void k_prep(const float* __restrict__ ov, const int* __restrict__ of,
                       const float* __restrict__ sv, const int* __restrict__ sf,
                       const float* __restrict__ r1, const float* __restrict__ r2,
                       unsigned int* __restrict__ ws, float4* __restrict__ ws4) {
  int i = blockIdx.x * blockDim.x + threadIdx.x;
  if (i < 4) ws[i] = 0u;                          // acc = 0.0f
  ws[WS_MINR + i] = 0x7f800000u;                  // +inf (grid == NPTS exactly)

  { // sample point i (face verts are 96 KB total -> L1/L2-hot gathers)
    int g = i >> 4;
    int a = sf[3*g], b = sf[3*g+1], c = sf[3*g+2];
    float sr = sqrtf(r1[i]);
    float u = 1.0f - sr;
    float v = sr * (1.0f - r2[i]);
    float w = sr * r2[i];
    float px = u*sv[3*a]   + v*sv[3*b]   + w*sv[3*c];
    float py = u*sv[3*a+1] + v*sv[3*b+1] + w*sv[3*c+1];
    float pz = u*sv[3*a+2] + v*sv[3*b+2] + w*sv[3*c+2];
    (ws4 + F4_PTS)[i] = make_float4(px, py, pz, fmaf(px, px, fmaf(py, py, pz*pz)));
  }
  if (i < G_F) { // simp barycenter (fwd query) + minf init
    ws[WS_MINF + i] = 0x7f800000u;
    int a = sf[3*i], b = sf[3*i+1], c = sf[3*i+2];
    float x = (sv[3*a] + sv[3*b] + sv[3*c]) * (1.0f/3.0f);
    float y = (sv[3*a+1] + sv[3*b+1] + sv[3*c+1]) * (1.0f/3.0f);
    float z = (sv[3*a+2] + sv[3*b+2] + sv[3*c+2]) * (1.0f/3.0f);
    (ws4 + F4_SB)[i] = make_float4(x, y, z, fmaf(x, x, fmaf(y, y, z*z)));
  }
  if (i < N_V) { // packed vertices (rev targets)
    float x = ov[3*i], y = ov[3*i+1], z = ov[3*i+2];
    pack_target(x, y, z, fmaf(x, x, fmaf(y, y, z*z)),
                (half8*)(ws4 + F4_PKV), i >> 5, i & 31);
  }
  if (i < N_F) { // packed orig barycenters (fwd targets)
    int a = of[3*i], b = of[3*i+1], c = of[3*i+2];
    float x = (ov[3*a] + ov[3*b] + ov[3*c]) * (1.0f/3.0f);
    float y = (ov[3*a+1] + ov[3*b+1] + ov[3*c+1]) * (1.0f/3.0f);
    float z = (ov[3*a+2] + ov[3*b+2] + ov[3*c+2]) * (1.0f/3.0f);
    pack_target(x, y, z, fmaf(x, x, fmaf(y, y, z*z)),
                (half8*)(ws4 + F4_PKO), i >> 5, i & 31);
  }
}

// MFMA min-distance kernel, LDS-staged (round-7-measured structure: MB=2,
// many blocks for barrier overlap), with the churn-free MFMA4_MIN asm core.
// Per chunk: 32 B-tiles async-staged to LDS, one barrier, then 8 iterations
// of (4 ds_read_b128 + 2 asm blocks).  launch_bounds(256,3): explicit arch
// liveness ~134 regs (64 pinned + rm 32 + frags/tiles/addr) <= 168 cap.
__global__ __launch_bounds__(256, 3) void k_min(const float4* __restrict__ q4,
                                                const half8* __restrict__ pk,
                                                unsigned int* __restrict__ minU,
                                                int nchunks) {
  __shared__ half8 sB[TILES * 64];   // 32 KB
  int lane  = threadIdx.x & 63;
  int wave  = threadIdx.x >> 6;
  int half_ = lane >> 5;
  int m     = lane & 31;
  int qbase = blockIdx.x * 256 + wave * (32 * MB);
  int tbase = blockIdx.y * nchunks * TILES;

  // A fragments (validated): A[m=lane&31][k=(lane>>5)*8+j]
  // half0: (p_hi,1, p_hi,1)   half1: (p_lo,0, 0,0,0,0)
  half8 afrag[MB];
  float psq[MB];
  #pragma unroll
  for (int mb = 0; mb < MB; ++mb) {
    float4 q = q4[qbase + mb*32 + m];
    psq[mb] = q.w;
    _Float16 hx = (_Float16)q.x, hy = (_Float16)q.y, hz = (_Float16)q.z;
    half8 a;
    if (half_ == 0) {
      a[0]=hx; a[1]=hy; a[2]=hz; a[3]=(_Float16)1.0f;
      a[4]=hx; a[5]=hy; a[6]=hz; a[7]=(_Float16)1.0f;
    } else {
      a[0]=(_Float16)(q.x-(float)hx); a[1]=(_Float16)(q.y-(float)hy);
      a[2]=(_Float16)(q.z-(float)hz); a[3]=(_Float16)0.0f;
      a[4]=(_Float16)0.0f; a[5]=(_Float16)0.0f; a[6]=(_Float16)0.0f; a[7]=(_Float16)0.0f;
    }
    afrag[mb] = a;
  }

  float inf = __uint_as_float(0x7f800000u);
  float rm0[16], rm1[16];
  #pragma unroll
  for (int r = 0; r < 16; ++r) { rm0[r] = inf; rm1[r] = inf; }

  for (int ch = 0; ch < nchunks; ++ch) {
    int t0 = tbase + ch * TILES;
    if (ch > 0) __syncthreads();   // prior sweep done before overwriting sB
    // async stage: wave w loads tiles w, w+4, ..., w+28 (1 KB each, lane*16B)
    const half8* src = pk + (size_t)(t0 + wave) * 64 + lane;
    #pragma unroll
    for (int j = 0; j < TILES/4; ++j) {
      __builtin_amdgcn_global_load_lds(
          (const __attribute__((address_space(1))) unsigned int*)(src + (size_t)j*256),
          (__attribute__((address_space(3))) unsigned int*)&sB[(wave + 4*j) * 64],
          16, 0, 0);
    }
    __syncthreads();               // vmcnt(0) drained -> tiles resident

    #pragma unroll
    for (int t = 0; t < TILES; t += 4) {
      half8 c0 = sB[(t+0)*64 + lane];      // ds_read_b128, conflict-free
      half8 c1 = sB[(t+1)*64 + lane];
      half8 c2 = sB[(t+2)*64 + lane];
      half8 c3 = sB[(t+3)*64 + lane];
      MFMA4_MIN(afrag[0], c0, c1, c2, c3, rm0);
      MFMA4_MIN(afrag[1], c0, c1, c2, c3, rm1);
    }
  }

  // min across 32 target-columns; write from lane m == row (no q4 reload).
  // C/D: col=lane&31, row=(reg&3)+8*(reg>>2)+4*(lane>>5)   (validated)
  #pragma unroll
  for (int mb = 0; mb < MB; ++mb) {
    float* rm = (mb == 0) ? rm0 : rm1;
    #pragma unroll
    for (int r = 0; r < 16; ++r) {
      float v = rm[r];
      v = fminf(v, __shfl_xor(v, 1, 64));
      v = fminf(v, __shfl_xor(v, 2, 64));
      v = fminf(v, __shfl_xor(v, 4, 64));
      v = fminf(v, __shfl_xor(v, 8, 64));
      v = fminf(v, __shfl_xor(v, 16, 64));
      int row = (r & 3) + 8*(r >> 2) + 4*half_;
      if (m == row) {
        float d2 = fmaxf(psq[mb] + v, 0.0f);
        atomicMin(&minU[qbase + mb*32 + m], __float_as_uint(d2));
      }
    }
  }
}

__device__ __forceinline__ float waveSum(float v) {
  #pragma unroll
  for (int o = 32; o > 0; o >>= 1) v += __shfl_down(v, o, 64);
  return v;
}
__device__ __forceinline__ float waveMax(float v) {
  #pragma unroll
  for (int o = 32; o > 0; o >>= 1) v = fmaxf(v, __shfl_down(v, o, 64));
  return v;
}

__global__ void k_reduce(const float* __restrict__ probs, const float* __restrict__ minf,
                         const float* __restrict__ minr, float* __restrict__ acc) {
  int tid = blockIdx.x * blockDim.x + threadIdx.x;
  int stride = gridDim.x * blockDim.x;
  float sf = 0.0f, sr = 0.0f, mx = 0.0f;
  for (int i = tid; i < NPTS; i += stride) {
    float d = sqrtf(fmaxf(minr[i], 1e-12f));
    sr = fmaf(probs[i >> 4], d, sr);
    mx = fmaxf(mx, d);
    if (i < G_F) {
      float df = sqrtf(fmaxf(minf[i], 1e-12f));
      sf = fmaf(probs[i], df, sf);
      sf = fmaf(1e-4f, 1.0f - probs[i], sf);
    }
  }
  __shared__ float lf[4], lr[4], lm[4];
  int lane = threadIdx.x & 63, wid = threadIdx.x >> 6;
  sf = waveSum(sf); sr = waveSum(sr); mx = waveMax(mx);
  if (lane == 0) { lf[wid] = sf; lr[wid] = sr; lm[wid] = mx; }
  __syncthreads();
  if (wid == 0) {
    float a = (lane < 4) ? lf[lane] : 0.0f;
    float b = (lane < 4) ? lr[lane] : 0.0f;
    float c = (lane < 4) ? lm[lane] : 0.0f;
    a = waveSum(a); b = waveSum(b); c = waveMax(c);
    if (lane == 0) {
      atomicAdd(&acc[0], a);
      atomicAdd(&acc[1], b);
      atomicMax((unsigned int*)&acc[2], __float_as_uint(c));
    }
  }
}

__global__ void k_final(const float* __restrict__ acc, float* __restrict__ out) {
  float maxd = acc[2] + 1e-8f;
  out[0] = acc[0] + acc[1] * 0.1f / maxd;
}

extern "C" void kernel_launch(void* const* d_in, const int* in_sizes, int n_in,
                              void* d_out, int out_size, void* d_ws, size_t ws_size,
                              hipStream_t stream) {
  const float* ov    = (const float*)d_in[0];
  const int*   of    = (const int*)  d_in[1];
  const float* sv    = (const float*)d_in[2];
  const int*   sfc   = (const int*)  d_in[3];
  const float* probs = (const float*)d_in[4];
  const float* r1    = (const float*)d_in[5];
  const float* r2    = (const float*)d_in[6];
  float*  ws  = (float*)d_ws;
  float4* ws4 = (float4*)d_ws;
  float*  out = (float*)d_out;

  float*        acc   = ws;
  float4*       sb4   = ws4 + F4_SB;
  float4*       pts4  = ws4 + F4_PTS;
  half8*        pkV   = (half8*)(ws4 + F4_PKV);
  half8*        pkO   = (half8*)(ws4 + F4_PKO);
  unsigned int* minfU = (unsigned int*)(ws + WS_MINF);
  unsigned int* minrU = (unsigned int*)(ws + WS_MINR);
  const float*  minfF = ws + WS_MINF;
  const float*  minrF = ws + WS_MINR;

  k_prep<<<NPTS/256, 256, 0, stream>>>(ov, of, sv, sfc, r1, r2,
                                       (unsigned int*)ws, ws4);
  // fwd: 8192 queries, 512 obary tiles; 32 x 16 blocks, 1 chunk each
  k_min<<<dim3(G_F/256, 16), 256, 0, stream>>>(sb4, pkO, minfU, 1);
  // rev: 131072 queries, 512 vert tiles; 512 x 8 blocks, 2 chunks each
  k_min<<<dim3(NPTS/256, 8), 256, 0, stream>>>(pts4, pkV, minrU, 2);
  k_reduce<<<256, 256, 0, stream>>>(probs, minfF, minrF, acc);
  k_final<<<1, 1, 0, stream>>>(acc, out);
}